// Round 1
// baseline (402.832 us; speedup 1.0000x reference)
//
#include <hip/hip_runtime.h>
#include <math.h>

// Problem constants
#define Bb   256
#define Nn   16384
#define Dd   512
#define NNZn 540672
#define DFf  2048

typedef __bf16 bf16;
typedef __bf16 bf16x4 __attribute__((ext_vector_type(4)));
typedef __bf16 bf16x8 __attribute__((ext_vector_type(8)));
typedef float  f32x4  __attribute__((ext_vector_type(4)));

// ---------------------------------------------------------------- async G->LDS
__device__ __forceinline__ void gload16(const void* g, void* l) {
  __builtin_amdgcn_global_load_lds(
      (const __attribute__((address_space(1))) unsigned int*)g,
      (__attribute__((address_space(3))) unsigned int*)l, 16, 0, 0);
}

// ---------------------------------------------------------------- fp32 -> bf16
__global__ __launch_bounds__(256) void k_cvt(const float* __restrict__ src,
                                             bf16* __restrict__ dst) {
  int base = (blockIdx.x * 256 + threadIdx.x) * 4;
  float4 v = *(const float4*)(src + base);
  bf16x4 o;
  o[0] = (bf16)v.x; o[1] = (bf16)v.y; o[2] = (bf16)v.z; o[3] = (bf16)v.w;
  *(bf16x4*)(dst + base) = o;
}

// ------------------------------------------------- x0 (B,N) -> x0T (N,B) bf16
__global__ __launch_bounds__(256) void k_transpose(const float* __restrict__ x0,
                                                   bf16* __restrict__ x0T) {
  __shared__ float tile[64][65];
  int n0 = blockIdx.x * 64, b0 = blockIdx.y * 64;
  int tx = threadIdx.x & 63, ty = threadIdx.x >> 6;   // ty 0..3
#pragma unroll
  for (int i = 0; i < 16; i++) {
    int bl = ty * 16 + i;
    tile[bl][tx] = x0[(size_t)(b0 + bl) * Nn + n0 + tx];
  }
  __syncthreads();
#pragma unroll
  for (int i = 0; i < 16; i++) {
    int nl = ty * 16 + i;
    x0T[(size_t)(n0 + nl) * Bb + b0 + tx] = (bf16)tile[tx][nl];
  }
}

// ---------------------------------------------------------------- CSR build
__global__ __launch_bounds__(256) void k_hist(const int* __restrict__ rows,
                                              int* __restrict__ counts) {
  int i = blockIdx.x * 256 + threadIdx.x;
  atomicAdd(&counts[rows[i]], 1);
}

__global__ __launch_bounds__(1024) void k_scan(const int* __restrict__ counts,
                                               int* __restrict__ starts,
                                               int* __restrict__ cursor) {
  __shared__ int sm[1024];
  int tid = threadIdx.x;
  int local[16];
  int s = 0;
#pragma unroll
  for (int i = 0; i < 16; i++) { local[i] = s; s += counts[tid * 16 + i]; }
  sm[tid] = s;
  __syncthreads();
  for (int d = 1; d < 1024; d <<= 1) {
    int v = (tid >= d) ? sm[tid - d] : 0;
    __syncthreads();
    sm[tid] += v;
    __syncthreads();
  }
  int off = sm[tid] - s;  // exclusive
#pragma unroll
  for (int i = 0; i < 16; i++) {
    int v = off + local[i];
    starts[tid * 16 + i] = v;
    cursor[tid * 16 + i] = v;
  }
}

__global__ __launch_bounds__(256) void k_scatter(const int* __restrict__ rows,
                                                 const int* __restrict__ cols,
                                                 const float* __restrict__ vals,
                                                 int* __restrict__ cursor,
                                                 int* __restrict__ cols_s,
                                                 float* __restrict__ vals_s) {
  int i = blockIdx.x * 256 + threadIdx.x;
  int r = rows[i];
  int p = atomicAdd(&cursor[r], 1);
  cols_s[p] = cols[i];
  vals_s[p] = vals[i];
}

// -------------------------- Lx[r][b] = sum_j val_j * x0[b][col_j]  (per row)
__global__ __launch_bounds__(256) void k_lx(const bf16* __restrict__ x0T,
                                            const int* __restrict__ starts,
                                            const int* __restrict__ counts,
                                            const int* __restrict__ cols_s,
                                            const float* __restrict__ vals_s,
                                            bf16* __restrict__ Lx) {
  int r = blockIdx.x;
  int b = threadIdx.x;
  __shared__ int   csm[256];
  __shared__ float vsm[256];
  int s0 = starts[r], cnt = counts[r];
  float acc = 0.f;
  for (int base = 0; base < cnt; base += 256) {
    int m = cnt - base; if (m > 256) m = 256;
    if (b < m) { csm[b] = cols_s[s0 + base + b]; vsm[b] = vals_s[s0 + base + b]; }
    __syncthreads();
    for (int i = 0; i < m; i++)
      acc += vsm[i] * (float)x0T[(size_t)csm[i] * Bb + b];
    __syncthreads();
  }
  Lx[(size_t)r * Bb + b] = (bf16)acc;
}

// ---------------- x_t[b][n] = x0[b][n] - 0.5*t[b]*Lx[n][b]   (bf16, B-major)
__global__ __launch_bounds__(256) void k_combine(const float* __restrict__ x0,
                                                 const bf16* __restrict__ Lx,
                                                 const float* __restrict__ t,
                                                 bf16* __restrict__ xt) {
  __shared__ float lxs[64][65];
  int n0 = blockIdx.x * 64, b0 = blockIdx.y * 64;
  int tx = threadIdx.x & 63, ty = threadIdx.x >> 6;
#pragma unroll
  for (int i = 0; i < 16; i++) {
    int nl = ty * 16 + i;
    lxs[nl][tx] = (float)Lx[(size_t)(n0 + nl) * Bb + b0 + tx];
  }
  __syncthreads();
#pragma unroll
  for (int i = 0; i < 16; i++) {
    int bl = ty * 16 + i;
    int b  = b0 + bl;
    float tc = t[b] * 0.5f;   // T_MAX
    float v = x0[(size_t)b * Nn + n0 + tx] - tc * lxs[tx][bl];
    xt[(size_t)b * Nn + n0 + tx] = (bf16)v;
  }
}

// ------------------------------------------------------------- bf16 TN GEMM
// C[m][n] (+)= sum_k A[m][k]*Bm[n][k].   MODE 0: atomicAdd (split-K)
//                                        MODE 1: direct store
//                                        MODE 2: fused loss sum((C+bias-x0)^2)
template <int BM, int BN, int MODE>
__global__ __launch_bounds__(256) void gemm_tn(
    const bf16* __restrict__ A, const bf16* __restrict__ Bm,
    float* __restrict__ C, int N, int K, int kLen,
    const float* __restrict__ bias, const float* __restrict__ x0,
    float* __restrict__ lossOut) {
  constexpr int WM = BM / 2, WN = BN / 2, FM = WM / 16, FN = WN / 16;
  constexpr int PA = (BM * 64) / 4096, PB = (BN * 64) / 4096;
  __shared__ __align__(16) bf16 As[BM * 32];
  __shared__ __align__(16) bf16 Bs[BN * 32];
  const int tid = threadIdx.x;
  const int lane = tid & 63, w = tid >> 6;
  const int wm = w >> 1, wn = w & 1;
  const int mBase = blockIdx.x * BM, nBase = blockIdx.y * BN;
  const int k0 = blockIdx.z * kLen;

  f32x4 acc[FM][FN];
#pragma unroll
  for (int i = 0; i < FM; i++)
#pragma unroll
    for (int j = 0; j < FN; j++) acc[i][j] = {0.f, 0.f, 0.f, 0.f};

  for (int kk = 0; kk < kLen; kk += 32) {
    const int k = k0 + kk;
    __syncthreads();
#pragma unroll
    for (int p = 0; p < PA; p++) {
      int u = p * 256 + tid;  // == p*256 + w*64 + lane
      gload16(A + (size_t)(mBase + (u >> 2)) * K + k + (u & 3) * 8,
              (char*)As + p * 4096 + w * 1024);
    }
#pragma unroll
    for (int p = 0; p < PB; p++) {
      int u = p * 256 + tid;
      gload16(Bm + (size_t)(nBase + (u >> 2)) * K + k + (u & 3) * 8,
              (char*)Bs + p * 4096 + w * 1024);
    }
    __syncthreads();
    bf16x8 af[FM], bfr[FN];
#pragma unroll
    for (int i = 0; i < FM; i++)
      af[i] = *(const bf16x8*)(As + (wm * WM + i * 16 + (lane & 15)) * 32 + (lane >> 4) * 8);
#pragma unroll
    for (int j = 0; j < FN; j++)
      bfr[j] = *(const bf16x8*)(Bs + (wn * WN + j * 16 + (lane & 15)) * 32 + (lane >> 4) * 8);
#pragma unroll
    for (int i = 0; i < FM; i++)
#pragma unroll
      for (int j = 0; j < FN; j++)
        acc[i][j] = __builtin_amdgcn_mfma_f32_16x16x32_bf16(af[i], bfr[j], acc[i][j], 0, 0, 0);
  }

  if constexpr (MODE == 0) {
#pragma unroll
    for (int i = 0; i < FM; i++)
#pragma unroll
      for (int j = 0; j < FN; j++) {
        int n  = nBase + wn * WN + j * 16 + (lane & 15);
        int mB = mBase + wm * WM + i * 16 + ((lane >> 4) << 2);
#pragma unroll
        for (int r = 0; r < 4; r++)
          atomicAdd(&C[(size_t)(mB + r) * N + n], acc[i][j][r]);
      }
  } else if constexpr (MODE == 1) {
#pragma unroll
    for (int i = 0; i < FM; i++)
#pragma unroll
      for (int j = 0; j < FN; j++) {
        int n  = nBase + wn * WN + j * 16 + (lane & 15);
        int mB = mBase + wm * WM + i * 16 + ((lane >> 4) << 2);
#pragma unroll
        for (int r = 0; r < 4; r++)
          C[(size_t)(mB + r) * N + n] = acc[i][j][r];
      }
  } else {
    float lsum = 0.f;
#pragma unroll
    for (int i = 0; i < FM; i++)
#pragma unroll
      for (int j = 0; j < FN; j++) {
        int n  = nBase + wn * WN + j * 16 + (lane & 15);
        float bo = bias[n];
        int mB = mBase + wm * WM + i * 16 + ((lane >> 4) << 2);
#pragma unroll
        for (int r = 0; r < 4; r++) {
          float d = acc[i][j][r] + bo - x0[(size_t)(mB + r) * N + n];
          lsum += d * d;
        }
      }
    for (int off = 32; off > 0; off >>= 1) lsum += __shfl_down(lsum, off, 64);
    if (lane == 0) atomicAdd(lossOut, lsum);
  }
}

// ------------- h = h_acc + b_in + time-embed; write fp32 + bf16
__global__ __launch_bounds__(512) void k_epi_h(const float* __restrict__ h_acc,
                                               const float* __restrict__ t,
                                               const float* __restrict__ W_t1,
                                               const float* __restrict__ b_t1,
                                               const float* __restrict__ W_t2,
                                               const float* __restrict__ b_t2,
                                               const float* __restrict__ b_in,
                                               float* __restrict__ h_f32,
                                               bf16* __restrict__ h_b) {
  int b = blockIdx.x, d = threadIdx.x;
  __shared__ float s[32];
  if (d < 32) {
    float z = t[b] * W_t1[d] + b_t1[d];   // t_norm == t
    s[d] = z / (1.f + expf(-z));          // silu
  }
  __syncthreads();
  float v = h_acc[b * Dd + d] + b_in[d] + b_t2[d];
#pragma unroll
  for (int j = 0; j < 32; j++) v += s[j] * W_t2[d * 32 + j];
  h_f32[b * Dd + d] = v;
  h_b[b * Dd + d] = (bf16)v;
}

__global__ __launch_bounds__(256) void k_epi_v(const float* __restrict__ acc,
                                               const float* __restrict__ b_qkv,
                                               bf16* __restrict__ out) {
  int i = blockIdx.x * 256 + threadIdx.x;  // 131072
  out[i] = (bf16)(acc[i] + b_qkv[2 * Dd + (i & (Dd - 1))]);
}

__global__ __launch_bounds__(256) void k_epi_f1(const float* __restrict__ acc,
                                                const float* __restrict__ b_f1,
                                                bf16* __restrict__ out) {
  int i = blockIdx.x * 256 + threadIdx.x;  // 524288
  float x = acc[i] + b_f1[i & (DFf - 1)];
  float g = 0.5f * x * (1.f + erff(x * 0.70710678118654752f));  // exact gelu
  out[i] = (bf16)g;
}

// ---------------- LayerNorm over D=512: x = base + add + bias; y = LN(x)*g+be
__global__ __launch_bounds__(512) void k_ln(const float* __restrict__ base,
                                            const float* __restrict__ add,
                                            const float* __restrict__ bias,
                                            const float* __restrict__ g,
                                            const float* __restrict__ be,
                                            float* __restrict__ out_f32,
                                            bf16* __restrict__ out_b) {
  int b = blockIdx.x, d = threadIdx.x;
  __shared__ float red[16];
  float x = base[b * Dd + d] + add[b * Dd + d] + bias[d];
  int w = d >> 6, lane = d & 63;
  float s = x;
  for (int off = 32; off > 0; off >>= 1) s += __shfl_down(s, off, 64);
  if (lane == 0) red[w] = s;
  __syncthreads();
  if (d == 0) {
    float tot = 0.f;
    for (int i = 0; i < 8; i++) tot += red[i];
    red[8] = tot * (1.f / 512.f);
  }
  __syncthreads();
  float mu = red[8];
  float c = x - mu;
  float s2 = c * c;
  for (int off = 32; off > 0; off >>= 1) s2 += __shfl_down(s2, off, 64);
  if (lane == 0) red[w] = s2;
  __syncthreads();
  if (d == 0) {
    float tot = 0.f;
    for (int i = 0; i < 8; i++) tot += red[i];
    red[8] = tot * (1.f / 512.f);
  }
  __syncthreads();
  float var = red[8];
  float y = c * rsqrtf(var + 1e-5f) * g[d] + be[d];
  if (out_f32) out_f32[b * Dd + d] = y;
  out_b[b * Dd + d] = (bf16)y;
}

__global__ void k_final(const float* __restrict__ loss, float* __restrict__ out) {
  if (threadIdx.x == 0 && blockIdx.x == 0)
    out[0] = loss[0] * (1.f / 4194304.f);  // mean over B*N
}

// ======================================================================= host
extern "C" void kernel_launch(void* const* d_in, const int* in_sizes, int n_in,
                              void* d_out, int out_size, void* d_ws, size_t ws_size,
                              hipStream_t stream) {
  const float* x0    = (const float*)d_in[0];
  const float* t     = (const float*)d_in[1];
  const float* Lv    = (const float*)d_in[2];
  const float* W_in  = (const float*)d_in[3];
  const float* b_in  = (const float*)d_in[4];
  const float* W_out = (const float*)d_in[5];
  const float* b_out = (const float*)d_in[6];
  const float* W_qkv = (const float*)d_in[7];
  const float* b_qkv = (const float*)d_in[8];
  const float* W_o   = (const float*)d_in[9];
  const float* b_o   = (const float*)d_in[10];
  const float* g1    = (const float*)d_in[11];
  const float* be1   = (const float*)d_in[12];
  const float* g2    = (const float*)d_in[13];
  const float* be2   = (const float*)d_in[14];
  const float* W_f1  = (const float*)d_in[15];
  const float* b_f1  = (const float*)d_in[16];
  const float* W_f2  = (const float*)d_in[17];
  const float* b_f2  = (const float*)d_in[18];
  const float* W_t1  = (const float*)d_in[19];
  const float* b_t1  = (const float*)d_in[20];
  const float* W_t2  = (const float*)d_in[21];
  const float* b_t2  = (const float*)d_in[22];
  const int* L_rows  = (const int*)d_in[23];
  const int* L_cols  = (const int*)d_in[24];

  size_t off = 0;
  char* ws = (char*)d_ws;
  auto carve = [&](size_t bytes) -> void* {
    void* p = ws + off;
    off += (bytes + 255) & ~(size_t)255;
    return p;
  };

  bf16* W_in_b   = (bf16*)carve((size_t)Dd * Nn * 2);
  bf16* W_out_b  = (bf16*)carve((size_t)Nn * Dd * 2);
  bf16* W_v_b    = (bf16*)carve((size_t)Dd * Dd * 2);
  bf16* W_o_b    = (bf16*)carve((size_t)Dd * Dd * 2);
  bf16* W_f1_b   = (bf16*)carve((size_t)DFf * Dd * 2);
  bf16* W_f2_b   = (bf16*)carve((size_t)Dd * DFf * 2);
  bf16* x0T_b    = (bf16*)carve((size_t)Nn * Bb * 2);
  bf16* Lx_b     = (bf16*)carve((size_t)Nn * Bb * 2);
  bf16* xt_b     = (bf16*)carve((size_t)Bb * Nn * 2);
  float* h_acc   = (float*)carve((size_t)Bb * Dd * 4);
  float* h_f32   = (float*)carve((size_t)Bb * Dd * 4);
  bf16* h_b      = (bf16*)carve((size_t)Bb * Dd * 2);
  float* v_acc   = (float*)carve((size_t)Bb * Dd * 4);
  bf16* v_b      = (bf16*)carve((size_t)Bb * Dd * 2);
  float* at_acc  = (float*)carve((size_t)Bb * Dd * 4);
  float* hln_f32 = (float*)carve((size_t)Bb * Dd * 4);
  bf16* hln_b    = (bf16*)carve((size_t)Bb * Dd * 2);
  float* f1_acc  = (float*)carve((size_t)Bb * DFf * 4);
  bf16* f1_b     = (bf16*)carve((size_t)Bb * DFf * 2);
  float* f2_acc  = (float*)carve((size_t)Bb * Dd * 4);
  bf16* h2_b     = (bf16*)carve((size_t)Bb * Dd * 2);
  int* counts    = (int*)carve((size_t)Nn * 4);
  int* starts    = (int*)carve((size_t)Nn * 4);
  int* cursor    = (int*)carve((size_t)Nn * 4);
  int* cols_s    = (int*)carve((size_t)NNZn * 4);
  float* vals_s  = (float*)carve((size_t)NNZn * 4);
  float* lossw   = (float*)carve(256);
  (void)in_sizes; (void)n_in; (void)out_size; (void)ws_size;

  // zero accumulators (ws is re-poisoned 0xAA before every call)
  hipMemsetAsync(counts, 0, (size_t)Nn * 4, stream);
  hipMemsetAsync(h_acc, 0, (size_t)Bb * Dd * 4, stream);
  hipMemsetAsync(v_acc, 0, (size_t)Bb * Dd * 4, stream);
  hipMemsetAsync(at_acc, 0, (size_t)Bb * Dd * 4, stream);
  hipMemsetAsync(f1_acc, 0, (size_t)Bb * DFf * 4, stream);
  hipMemsetAsync(f2_acc, 0, (size_t)Bb * Dd * 4, stream);
  hipMemsetAsync(lossw, 0, 4, stream);

  // weight conversions fp32->bf16
  k_cvt<<<8192, 256, 0, stream>>>(W_in, W_in_b);
  k_cvt<<<8192, 256, 0, stream>>>(W_out, W_out_b);
  k_cvt<<<256, 256, 0, stream>>>(W_qkv + (size_t)2 * Dd * Dd, W_v_b);  // v-rows only
  k_cvt<<<256, 256, 0, stream>>>(W_o, W_o_b);
  k_cvt<<<1024, 256, 0, stream>>>(W_f1, W_f1_b);
  k_cvt<<<1024, 256, 0, stream>>>(W_f2, W_f2_b);

  // sparse: x0T, CSR, Lx, x_t
  k_transpose<<<dim3(256, 4), 256, 0, stream>>>(x0, x0T_b);
  k_hist<<<NNZn / 256, 256, 0, stream>>>(L_rows, counts);
  k_scan<<<1, 1024, 0, stream>>>(counts, starts, cursor);
  k_scatter<<<NNZn / 256, 256, 0, stream>>>(L_rows, L_cols, Lv, cursor, cols_s, vals_s);
  k_lx<<<Nn, 256, 0, stream>>>(x0T_b, starts, counts, cols_s, vals_s, Lx_b);
  k_combine<<<dim3(256, 4), 256, 0, stream>>>(x0, Lx_b, t, xt_b);

  // h = x_t @ W_in^T   (M=256,N=512,K=16384, split-K=32)
  gemm_tn<128, 128, 0><<<dim3(2, 4, 32), 256, 0, stream>>>(
      xt_b, W_in_b, h_acc, Dd, Nn, 512, nullptr, nullptr, nullptr);
  k_epi_h<<<Bb, 512, 0, stream>>>(h_acc, t, W_t1, b_t1, W_t2, b_t2, b_in, h_f32, h_b);

  // v = h @ W_qkv_v^T  (K=512, split-K=4)
  gemm_tn<64, 64, 0><<<dim3(4, 8, 4), 256, 0, stream>>>(
      h_b, W_v_b, v_acc, Dd, Dd, 128, nullptr, nullptr, nullptr);
  k_epi_v<<<512, 256, 0, stream>>>(v_acc, b_qkv, v_b);

  // attn_out = v @ W_o^T
  gemm_tn<64, 64, 0><<<dim3(4, 8, 4), 256, 0, stream>>>(
      v_b, W_o_b, at_acc, Dd, Dd, 128, nullptr, nullptr, nullptr);
  k_ln<<<Bb, 512, 0, stream>>>(h_f32, at_acc, b_o, g1, be1, hln_f32, hln_b);

  // ff1 = gelu(hln @ W_f1^T + b_f1)
  gemm_tn<64, 64, 0><<<dim3(4, 32, 4), 256, 0, stream>>>(
      hln_b, W_f1_b, f1_acc, DFf, Dd, 128, nullptr, nullptr, nullptr);
  k_epi_f1<<<2048, 256, 0, stream>>>(f1_acc, b_f1, f1_b);

  // ff2 = ff1 @ W_f2^T  (K=2048, split-K=16)
  gemm_tn<64, 64, 0><<<dim3(4, 8, 16), 256, 0, stream>>>(
      f1_b, W_f2_b, f2_acc, Dd, DFf, 128, nullptr, nullptr, nullptr);
  k_ln<<<Bb, 512, 0, stream>>>(hln_f32, f2_acc, b_f2, g2, be2, nullptr, h2_b);

  // pred = h2 @ W_out^T + b_out, fused loss
  gemm_tn<128, 128, 2><<<dim3(2, 128, 1), 256, 0, stream>>>(
      h2_b, W_out_b, nullptr, Nn, Dd, 512, b_out, x0, lossw);
  k_final<<<1, 64, 0, stream>>>(lossw, (float*)d_out);
}

// Round 2
// 395.417 us; speedup vs baseline: 1.0188x; 1.0188x over previous
//
#include <hip/hip_runtime.h>
#include <math.h>

// Problem constants
#define Bb   256
#define Nn   16384
#define Dd   512
#define NNZn 540672
#define DFf  2048

typedef __bf16 bf16;
typedef __bf16 bf16x4 __attribute__((ext_vector_type(4)));
typedef __bf16 bf16x8 __attribute__((ext_vector_type(8)));
typedef float  f32x4  __attribute__((ext_vector_type(4)));

// ---------------------------------------------------------------- async G->LDS
__device__ __forceinline__ void gload16(const void* g, void* l) {
  __builtin_amdgcn_global_load_lds(
      (const __attribute__((address_space(1))) unsigned int*)g,
      (__attribute__((address_space(3))) unsigned int*)l, 16, 0, 0);
}

// ---------------------------------------- all weight fp32->bf16 in one kernel
__global__ __launch_bounds__(256) void k_cvt_all(
    const float* __restrict__ w_in, const float* __restrict__ w_out,
    const float* __restrict__ w_v, const float* __restrict__ w_o,
    const float* __restrict__ w_f1, const float* __restrict__ w_f2,
    bf16* __restrict__ o_in, bf16* __restrict__ o_out, bf16* __restrict__ o_v,
    bf16* __restrict__ o_o, bf16* __restrict__ o_f1, bf16* __restrict__ o_f2) {
  int v = blockIdx.x * 256 + threadIdx.x;  // vec4 index, 4849664 total
  const float* s; bf16* d; int base;
  if (v < 4194304) {
    if (v < 2097152) { s = w_in;  d = o_in;  base = 0; }
    else             { s = w_out; d = o_out; base = 2097152; }
  } else if (v < 4325376) {
    if (v < 4259840) { s = w_v;   d = o_v;   base = 4194304; }
    else             { s = w_o;   d = o_o;   base = 4259840; }
  } else {
    if (v < 4587520) { s = w_f1;  d = o_f1;  base = 4325376; }
    else             { s = w_f2;  d = o_f2;  base = 4587520; }
  }
  int idx = (v - base) * 4;
  float4 x = *(const float4*)(s + idx);
  bf16x4 o;
  o[0] = (bf16)x.x; o[1] = (bf16)x.y; o[2] = (bf16)x.z; o[3] = (bf16)x.w;
  *(bf16x4*)(d + idx) = o;
}

// ------------------------------------------------- x0 (B,N) -> x0T (N,B) bf16
__global__ __launch_bounds__(256) void k_transpose(const float* __restrict__ x0,
                                                   bf16* __restrict__ x0T) {
  __shared__ float tile[64][65];
  int n0 = blockIdx.x * 64, b0 = blockIdx.y * 64;
  int tx = threadIdx.x & 63, ty = threadIdx.x >> 6;   // ty 0..3
#pragma unroll
  for (int i = 0; i < 16; i++) {
    int bl = ty * 16 + i;
    tile[bl][tx] = x0[(size_t)(b0 + bl) * Nn + n0 + tx];
  }
  __syncthreads();
#pragma unroll
  for (int i = 0; i < 16; i++) {
    int nl = ty * 16 + i;
    x0T[(size_t)(n0 + nl) * Bb + b0 + tx] = (bf16)tile[tx][nl];
  }
}

// ---------------------------------------------------------------- CSR build
__global__ __launch_bounds__(256) void k_hist(const int* __restrict__ rows,
                                              int* __restrict__ counts) {
  int i = blockIdx.x * 256 + threadIdx.x;
  atomicAdd(&counts[rows[i]], 1);
}

__global__ __launch_bounds__(1024) void k_scan(const int* __restrict__ counts,
                                               int* __restrict__ starts,
                                               int* __restrict__ cursor) {
  __shared__ int sm[1024];
  int tid = threadIdx.x;
  int local[16];
  int s = 0;
#pragma unroll
  for (int i = 0; i < 16; i++) { local[i] = s; s += counts[tid * 16 + i]; }
  sm[tid] = s;
  __syncthreads();
  for (int d = 1; d < 1024; d <<= 1) {
    int v = (tid >= d) ? sm[tid - d] : 0;
    __syncthreads();
    sm[tid] += v;
    __syncthreads();
  }
  int off = sm[tid] - s;  // exclusive
#pragma unroll
  for (int i = 0; i < 16; i++) {
    int v = off + local[i];
    starts[tid * 16 + i] = v;
    cursor[tid * 16 + i] = v;
  }
}

__global__ __launch_bounds__(256) void k_scatter(const int* __restrict__ rows,
                                                 const int* __restrict__ cols,
                                                 const float* __restrict__ vals,
                                                 int* __restrict__ cursor,
                                                 int* __restrict__ cols_s,
                                                 float* __restrict__ vals_s) {
  int i = blockIdx.x * 256 + threadIdx.x;
  int r = rows[i];
  int p = atomicAdd(&cursor[r], 1);
  cols_s[p] = cols[i];
  vals_s[p] = vals[i];
}

// ------ Lx[r][b] = sum_j val_j * x0[b][col_j].  Batch split into two 128-lane
// halves so each half's gather footprint (4.2 MB) fits one XCD's 4 MB L2;
// grid(2,N) puts half 0 on even linear block ids -> even XCDs (round-robin).
__global__ __launch_bounds__(128) void k_lx(const bf16* __restrict__ x0T,
                                            const int* __restrict__ starts,
                                            const int* __restrict__ counts,
                                            const int* __restrict__ cols_s,
                                            const float* __restrict__ vals_s,
                                            bf16* __restrict__ Lx) {
  int r = blockIdx.y;
  int b = blockIdx.x * 128 + threadIdx.x;
  __shared__ int   csm[256];
  __shared__ float vsm[256];
  int s0 = starts[r], cnt = counts[r];
  float a0 = 0.f, a1 = 0.f;
  for (int base = 0; base < cnt; base += 256) {
    int m = cnt - base; if (m > 256) m = 256;
    for (int j = threadIdx.x; j < m; j += 128) {
      csm[j] = cols_s[s0 + base + j];
      vsm[j] = vals_s[s0 + base + j];
    }
    __syncthreads();
    int i = 0;
    for (; i + 1 < m; i += 2) {
      a0 += vsm[i]     * (float)x0T[(size_t)csm[i]     * Bb + b];
      a1 += vsm[i + 1] * (float)x0T[(size_t)csm[i + 1] * Bb + b];
    }
    if (i < m) a0 += vsm[i] * (float)x0T[(size_t)csm[i] * Bb + b];
    __syncthreads();
  }
  Lx[(size_t)r * Bb + b] = (bf16)(a0 + a1);
}

// ---------------- x_t[b][n] = x0[b][n] - 0.5*t[b]*Lx[n][b]   (bf16, B-major)
__global__ __launch_bounds__(256) void k_combine(const float* __restrict__ x0,
                                                 const bf16* __restrict__ Lx,
                                                 const float* __restrict__ t,
                                                 bf16* __restrict__ xt) {
  __shared__ float lxs[64][65];
  int n0 = blockIdx.x * 64, b0 = blockIdx.y * 64;
  int tx = threadIdx.x & 63, ty = threadIdx.x >> 6;
#pragma unroll
  for (int i = 0; i < 16; i++) {
    int nl = ty * 16 + i;
    lxs[nl][tx] = (float)Lx[(size_t)(n0 + nl) * Bb + b0 + tx];
  }
  __syncthreads();
#pragma unroll
  for (int i = 0; i < 16; i++) {
    int bl = ty * 16 + i;
    int b  = b0 + bl;
    float tc = t[b] * 0.5f;   // T_MAX
    float v = x0[(size_t)b * Nn + n0 + tx] - tc * lxs[tx][bl];
    xt[(size_t)b * Nn + n0 + tx] = (bf16)v;
  }
}

// ------------------------------------------------------------- bf16 TN GEMM
// C[m][n] = sum_k A[m][k]*Bm[n][k].  MODE 0: store split-K partial at z*MN
//                                    MODE 2: fused loss sum((C+bias-x0)^2)
template <int BM, int BN, int MODE>
__global__ __launch_bounds__(256) void gemm_tn(
    const bf16* __restrict__ A, const bf16* __restrict__ Bm,
    float* __restrict__ C, int N, int K, int kLen, int MN,
    const float* __restrict__ bias, const float* __restrict__ x0,
    float* __restrict__ lossOut) {
  constexpr int WM = BM / 2, WN = BN / 2, FM = WM / 16, FN = WN / 16;
  constexpr int PA = (BM * 64) / 4096, PB = (BN * 64) / 4096;
  __shared__ __align__(16) bf16 As[BM * 32];
  __shared__ __align__(16) bf16 Bs[BN * 32];
  const int tid = threadIdx.x;
  const int lane = tid & 63, w = tid >> 6;
  const int wm = w >> 1, wn = w & 1;
  const int mBase = blockIdx.x * BM, nBase = blockIdx.y * BN;
  const int k0 = blockIdx.z * kLen;

  f32x4 acc[FM][FN];
#pragma unroll
  for (int i = 0; i < FM; i++)
#pragma unroll
    for (int j = 0; j < FN; j++) acc[i][j] = {0.f, 0.f, 0.f, 0.f};

  for (int kk = 0; kk < kLen; kk += 32) {
    const int k = k0 + kk;
    __syncthreads();
#pragma unroll
    for (int p = 0; p < PA; p++) {
      int u = p * 256 + tid;  // == p*256 + w*64 + lane
      gload16(A + (size_t)(mBase + (u >> 2)) * K + k + (u & 3) * 8,
              (char*)As + p * 4096 + w * 1024);
    }
#pragma unroll
    for (int p = 0; p < PB; p++) {
      int u = p * 256 + tid;
      gload16(Bm + (size_t)(nBase + (u >> 2)) * K + k + (u & 3) * 8,
              (char*)Bs + p * 4096 + w * 1024);
    }
    __syncthreads();
    bf16x8 af[FM], bfr[FN];
#pragma unroll
    for (int i = 0; i < FM; i++)
      af[i] = *(const bf16x8*)(As + (wm * WM + i * 16 + (lane & 15)) * 32 + (lane >> 4) * 8);
#pragma unroll
    for (int j = 0; j < FN; j++)
      bfr[j] = *(const bf16x8*)(Bs + (wn * WN + j * 16 + (lane & 15)) * 32 + (lane >> 4) * 8);
#pragma unroll
    for (int i = 0; i < FM; i++)
#pragma unroll
      for (int j = 0; j < FN; j++)
        acc[i][j] = __builtin_amdgcn_mfma_f32_16x16x32_bf16(af[i], bfr[j], acc[i][j], 0, 0, 0);
  }

  if constexpr (MODE == 0) {
    float* Cz = C + (size_t)blockIdx.z * MN;
#pragma unroll
    for (int i = 0; i < FM; i++)
#pragma unroll
      for (int j = 0; j < FN; j++) {
        int n  = nBase + wn * WN + j * 16 + (lane & 15);
        int mB = mBase + wm * WM + i * 16 + ((lane >> 4) << 2);
#pragma unroll
        for (int r = 0; r < 4; r++)
          Cz[(size_t)(mB + r) * N + n] = acc[i][j][r];
      }
  } else {
    float lsum = 0.f;
#pragma unroll
    for (int i = 0; i < FM; i++)
#pragma unroll
      for (int j = 0; j < FN; j++) {
        int n  = nBase + wn * WN + j * 16 + (lane & 15);
        float bo = bias[n];
        int mB = mBase + wm * WM + i * 16 + ((lane >> 4) << 2);
#pragma unroll
        for (int r = 0; r < 4; r++) {
          float d = acc[i][j][r] + bo - x0[(size_t)(mB + r) * N + n];
          lsum += d * d;
        }
      }
    for (int off = 32; off > 0; off >>= 1) lsum += __shfl_down(lsum, off, 64);
    if (lane == 0) atomicAdd(lossOut, lsum);
  }
}

// ------------- h = sum_32 partials + b_in + time-embed; write fp32 + bf16
__global__ __launch_bounds__(512) void k_epi_h(const float* __restrict__ P,
                                               const float* __restrict__ t,
                                               const float* __restrict__ W_t1,
                                               const float* __restrict__ b_t1,
                                               const float* __restrict__ W_t2,
                                               const float* __restrict__ b_t2,
                                               const float* __restrict__ b_in,
                                               float* __restrict__ h_f32,
                                               bf16* __restrict__ h_b) {
  int b = blockIdx.x, d = threadIdx.x;
  __shared__ float s[32];
  if (d < 32) {
    float z = t[b] * W_t1[d] + b_t1[d];   // t_norm == t
    s[d] = z / (1.f + expf(-z));          // silu
  }
  __syncthreads();
  int i = b * Dd + d;
  float v = b_in[d] + b_t2[d];
#pragma unroll
  for (int sp = 0; sp < 32; sp++) v += P[sp * (Bb * Dd) + i];
#pragma unroll
  for (int j = 0; j < 32; j++) v += s[j] * W_t2[d * 32 + j];
  h_f32[i] = v;
  h_b[i] = (bf16)v;
}

__global__ __launch_bounds__(256) void k_epi_v(const float* __restrict__ P,
                                               const float* __restrict__ b_qkv,
                                               bf16* __restrict__ out) {
  int i = blockIdx.x * 256 + threadIdx.x;  // 131072
  float v = b_qkv[2 * Dd + (i & (Dd - 1))];
#pragma unroll
  for (int sp = 0; sp < 4; sp++) v += P[sp * (Bb * Dd) + i];
  out[i] = (bf16)v;
}

__global__ __launch_bounds__(256) void k_epi_f1(const float* __restrict__ P,
                                                const float* __restrict__ b_f1,
                                                bf16* __restrict__ out) {
  int i = blockIdx.x * 256 + threadIdx.x;  // 524288
  float x = b_f1[i & (DFf - 1)];
#pragma unroll
  for (int sp = 0; sp < 4; sp++) x += P[sp * (Bb * DFf) + i];
  float g = 0.5f * x * (1.f + erff(x * 0.70710678118654752f));  // exact gelu
  out[i] = (bf16)g;
}

// -------- LayerNorm over D=512: x = base + sum_S add + bias; y = LN(x)*g+be
template <int NS>
__global__ __launch_bounds__(512) void k_ln(const float* __restrict__ base,
                                            const float* __restrict__ add,
                                            const float* __restrict__ bias,
                                            const float* __restrict__ g,
                                            const float* __restrict__ be,
                                            float* __restrict__ out_f32,
                                            bf16* __restrict__ out_b) {
  int b = blockIdx.x, d = threadIdx.x;
  __shared__ float red[16];
  int i = b * Dd + d;
  float x = base[i] + bias[d];
#pragma unroll
  for (int sp = 0; sp < NS; sp++) x += add[sp * (Bb * Dd) + i];
  int w = d >> 6, lane = d & 63;
  float s = x;
  for (int off = 32; off > 0; off >>= 1) s += __shfl_down(s, off, 64);
  if (lane == 0) red[w] = s;
  __syncthreads();
  if (d == 0) {
    float tot = 0.f;
    for (int q = 0; q < 8; q++) tot += red[q];
    red[8] = tot * (1.f / 512.f);
  }
  __syncthreads();
  float mu = red[8];
  float c = x - mu;
  float s2 = c * c;
  for (int off = 32; off > 0; off >>= 1) s2 += __shfl_down(s2, off, 64);
  if (lane == 0) red[w] = s2;
  __syncthreads();
  if (d == 0) {
    float tot = 0.f;
    for (int q = 0; q < 8; q++) tot += red[q];
    red[8] = tot * (1.f / 512.f);
  }
  __syncthreads();
  float var = red[8];
  float y = c * rsqrtf(var + 1e-5f) * g[d] + be[d];
  if (out_f32) out_f32[i] = y;
  out_b[i] = (bf16)y;
}

__global__ void k_final(const float* __restrict__ loss, float* __restrict__ out) {
  if (threadIdx.x == 0 && blockIdx.x == 0)
    out[0] = loss[0] * (1.f / 4194304.f);  // mean over B*N
}

// ======================================================================= host
extern "C" void kernel_launch(void* const* d_in, const int* in_sizes, int n_in,
                              void* d_out, int out_size, void* d_ws, size_t ws_size,
                              hipStream_t stream) {
  const float* x0    = (const float*)d_in[0];
  const float* t     = (const float*)d_in[1];
  const float* Lv    = (const float*)d_in[2];
  const float* W_in  = (const float*)d_in[3];
  const float* b_in  = (const float*)d_in[4];
  const float* W_out = (const float*)d_in[5];
  const float* b_out = (const float*)d_in[6];
  const float* W_qkv = (const float*)d_in[7];
  const float* b_qkv = (const float*)d_in[8];
  const float* W_o   = (const float*)d_in[9];
  const float* b_o   = (const float*)d_in[10];
  const float* g1    = (const float*)d_in[11];
  const float* be1   = (const float*)d_in[12];
  const float* g2    = (const float*)d_in[13];
  const float* be2   = (const float*)d_in[14];
  const float* W_f1  = (const float*)d_in[15];
  const float* b_f1  = (const float*)d_in[16];
  const float* W_f2  = (const float*)d_in[17];
  const float* b_f2  = (const float*)d_in[18];
  const float* W_t1  = (const float*)d_in[19];
  const float* b_t1  = (const float*)d_in[20];
  const float* W_t2  = (const float*)d_in[21];
  const float* b_t2  = (const float*)d_in[22];
  const int* L_rows  = (const int*)d_in[23];
  const int* L_cols  = (const int*)d_in[24];

  size_t off = 0;
  char* ws = (char*)d_ws;
  auto carve = [&](size_t bytes) -> void* {
    void* p = ws + off;
    off += (bytes + 255) & ~(size_t)255;
    return p;
  };

  bf16* W_in_b   = (bf16*)carve((size_t)Dd * Nn * 2);
  bf16* W_out_b  = (bf16*)carve((size_t)Nn * Dd * 2);
  bf16* W_v_b    = (bf16*)carve((size_t)Dd * Dd * 2);
  bf16* W_o_b    = (bf16*)carve((size_t)Dd * Dd * 2);
  bf16* W_f1_b   = (bf16*)carve((size_t)DFf * Dd * 2);
  bf16* W_f2_b   = (bf16*)carve((size_t)Dd * DFf * 2);
  bf16* x0T_b    = (bf16*)carve((size_t)Nn * Bb * 2);
  bf16* Lx_b     = (bf16*)carve((size_t)Nn * Bb * 2);
  bf16* xt_b     = (bf16*)carve((size_t)Bb * Nn * 2);
  float* p_h     = (float*)carve((size_t)32 * Bb * Dd * 4);   // 16 MB
  float* p_v     = (float*)carve((size_t)4 * Bb * Dd * 4);    //  2 MB
  float* p_at    = (float*)carve((size_t)4 * Bb * Dd * 4);    //  2 MB
  float* p_f1    = (float*)carve((size_t)4 * Bb * DFf * 4);   //  8 MB
  float* p_f2    = (float*)carve((size_t)16 * Bb * Dd * 4);   //  8 MB
  float* h_f32   = (float*)carve((size_t)Bb * Dd * 4);
  bf16* h_b      = (bf16*)carve((size_t)Bb * Dd * 2);
  bf16* v_b      = (bf16*)carve((size_t)Bb * Dd * 2);
  float* hln_f32 = (float*)carve((size_t)Bb * Dd * 4);
  bf16* hln_b    = (bf16*)carve((size_t)Bb * Dd * 2);
  bf16* f1_b     = (bf16*)carve((size_t)Bb * DFf * 2);
  bf16* h2_b     = (bf16*)carve((size_t)Bb * Dd * 2);
  int* counts    = (int*)carve((size_t)Nn * 4);
  float* lossw   = (float*)carve(256);
  int* starts    = (int*)carve((size_t)Nn * 4);
  int* cursor    = (int*)carve((size_t)Nn * 4);
  int* cols_s    = (int*)carve((size_t)NNZn * 4);
  float* vals_s  = (float*)carve((size_t)NNZn * 4);
  (void)in_sizes; (void)n_in; (void)out_size; (void)ws_size;

  // counts + lossw are adjacent: one memset covers both
  hipMemsetAsync(counts, 0, (size_t)Nn * 4 + 256, stream);

  // weight conversions fp32->bf16 (single kernel)
  k_cvt_all<<<18944, 256, 0, stream>>>(
      W_in, W_out, W_qkv + (size_t)2 * Dd * Dd, W_o, W_f1, W_f2,
      W_in_b, W_out_b, W_v_b, W_o_b, W_f1_b, W_f2_b);

  // sparse: x0T, CSR, Lx, x_t
  k_transpose<<<dim3(256, 4), 256, 0, stream>>>(x0, x0T_b);
  k_hist<<<NNZn / 256, 256, 0, stream>>>(L_rows, counts);
  k_scan<<<1, 1024, 0, stream>>>(counts, starts, cursor);
  k_scatter<<<NNZn / 256, 256, 0, stream>>>(L_rows, L_cols, Lv, cursor, cols_s, vals_s);
  k_lx<<<dim3(2, Nn), 128, 0, stream>>>(x0T_b, starts, counts, cols_s, vals_s, Lx_b);
  k_combine<<<dim3(256, 4), 256, 0, stream>>>(x0, Lx_b, t, xt_b);

  // h = x_t @ W_in^T   (M=256,N=512,K=16384, split-K=32, partial stores)
  gemm_tn<128, 128, 0><<<dim3(2, 4, 32), 256, 0, stream>>>(
      xt_b, W_in_b, p_h, Dd, Nn, 512, Bb * Dd, nullptr, nullptr, nullptr);
  k_epi_h<<<Bb, 512, 0, stream>>>(p_h, t, W_t1, b_t1, W_t2, b_t2, b_in, h_f32, h_b);

  // v = h @ W_qkv_v^T  (K=512, split-K=4)
  gemm_tn<64, 64, 0><<<dim3(4, 8, 4), 256, 0, stream>>>(
      h_b, W_v_b, p_v, Dd, Dd, 128, Bb * Dd, nullptr, nullptr, nullptr);
  k_epi_v<<<512, 256, 0, stream>>>(p_v, b_qkv, v_b);

  // attn_out = v @ W_o^T
  gemm_tn<64, 64, 0><<<dim3(4, 8, 4), 256, 0, stream>>>(
      v_b, W_o_b, p_at, Dd, Dd, 128, Bb * Dd, nullptr, nullptr, nullptr);
  k_ln<4><<<Bb, 512, 0, stream>>>(h_f32, p_at, b_o, g1, be1, hln_f32, hln_b);

  // ff1 = gelu(hln @ W_f1^T + b_f1)
  gemm_tn<64, 64, 0><<<dim3(4, 32, 4), 256, 0, stream>>>(
      hln_b, W_f1_b, p_f1, DFf, Dd, 128, Bb * DFf, nullptr, nullptr, nullptr);
  k_epi_f1<<<2048, 256, 0, stream>>>(p_f1, b_f1, f1_b);

  // ff2 = ff1 @ W_f2^T  (K=2048, split-K=16)
  gemm_tn<64, 64, 0><<<dim3(4, 8, 16), 256, 0, stream>>>(
      f1_b, W_f2_b, p_f2, Dd, DFf, 128, Bb * Dd, nullptr, nullptr, nullptr);
  k_ln<16><<<Bb, 512, 0, stream>>>(hln_f32, p_f2, b_f2, g2, be2, nullptr, h2_b);

  // pred = h2 @ W_out^T + b_out, fused loss
  gemm_tn<128, 128, 2><<<dim3(2, 128, 1), 256, 0, stream>>>(
      h2_b, W_out_b, nullptr, Nn, Dd, 512, 0, b_out, x0, lossw);
  k_final<<<1, 64, 0, stream>>>(lossw, (float*)d_out);
}

// Round 3
// 338.227 us; speedup vs baseline: 1.1910x; 1.1691x over previous
//
#include <hip/hip_runtime.h>
#include <math.h>

// Problem constants
#define Bb   256
#define Nn   16384
#define Dd   512
#define NNZn 540672
#define DFf  2048
#define SLOT 128   // padded CSR bucket width (max row count ~58 for Binom(540672,1/16384))

typedef __bf16 bf16;
typedef __bf16 bf16x4 __attribute__((ext_vector_type(4)));
typedef __bf16 bf16x8 __attribute__((ext_vector_type(8)));
typedef float  f32x4  __attribute__((ext_vector_type(4)));

// ---------------------------------------------------------------- async G->LDS
__device__ __forceinline__ void gload16(const void* g, void* l) {
  __builtin_amdgcn_global_load_lds(
      (const __attribute__((address_space(1))) unsigned int*)g,
      (__attribute__((address_space(3))) unsigned int*)l, 16, 0, 0);
}

// ---------------------------------------- all weight fp32->bf16 in one kernel
__global__ __launch_bounds__(256) void k_cvt_all(
    const float* __restrict__ w_in, const float* __restrict__ w_out,
    const float* __restrict__ w_v, const float* __restrict__ w_o,
    const float* __restrict__ w_f1, const float* __restrict__ w_f2,
    bf16* __restrict__ o_in, bf16* __restrict__ o_out, bf16* __restrict__ o_v,
    bf16* __restrict__ o_o, bf16* __restrict__ o_f1, bf16* __restrict__ o_f2) {
  int v = blockIdx.x * 256 + threadIdx.x;  // vec4 index, 4849664 total
  const float* s; bf16* d; int base;
  if (v < 4194304) {
    if (v < 2097152) { s = w_in;  d = o_in;  base = 0; }
    else             { s = w_out; d = o_out; base = 2097152; }
  } else if (v < 4325376) {
    if (v < 4259840) { s = w_v;   d = o_v;   base = 4194304; }
    else             { s = w_o;   d = o_o;   base = 4259840; }
  } else {
    if (v < 4587520) { s = w_f1;  d = o_f1;  base = 4325376; }
    else             { s = w_f2;  d = o_f2;  base = 4587520; }
  }
  int idx = (v - base) * 4;
  float4 x = *(const float4*)(s + idx);
  bf16x4 o;
  o[0] = (bf16)x.x; o[1] = (bf16)x.y; o[2] = (bf16)x.z; o[3] = (bf16)x.w;
  *(bf16x4*)(d + idx) = o;
}

// ------------------------------------------------- x0 (B,N) -> x0T (N,B) bf16
__global__ __launch_bounds__(256) void k_transpose(const float* __restrict__ x0,
                                                   bf16* __restrict__ x0T) {
  __shared__ float tile[64][65];
  int n0 = blockIdx.x * 64, b0 = blockIdx.y * 64;
  int tx = threadIdx.x & 63, ty = threadIdx.x >> 6;   // ty 0..3
#pragma unroll
  for (int i = 0; i < 16; i++) {
    int bl = ty * 16 + i;
    tile[bl][tx] = x0[(size_t)(b0 + bl) * Nn + n0 + tx];
  }
  __syncthreads();
#pragma unroll
  for (int i = 0; i < 16; i++) {
    int nl = ty * 16 + i;
    x0T[(size_t)(n0 + nl) * Bb + b0 + tx] = (bf16)tile[tx][nl];
  }
}

// ----------------------------- padded-bucket CSR: one pass, no scan/scatter
__global__ __launch_bounds__(256) void k_bucket(const int* __restrict__ rows,
                                                const int* __restrict__ cols,
                                                const float* __restrict__ vals,
                                                int* __restrict__ counts,
                                                int* __restrict__ cols_p,
                                                float* __restrict__ vals_p) {
  int i = blockIdx.x * 256 + threadIdx.x;
  int r = rows[i];
  int p = atomicAdd(&counts[r], 1);
  if (p < SLOT) {
    cols_p[(size_t)r * SLOT + p] = cols[i];
    vals_p[(size_t)r * SLOT + p] = vals[i];
  }
}

// ---- Lx[r][:] = sum_j val_j * x0T[col_j][:].  One WAVE per row; each lane
// holds 4 batch elems (bf16x4, 8 B) so one gather instr pulls the full 512 B
// row. Wave-synchronous LDS staging (no barriers). 2-way unroll for MLP.
__global__ __launch_bounds__(256) void k_lx(const bf16x4* __restrict__ x0T4,
                                            const int* __restrict__ counts,
                                            const int* __restrict__ cols_p,
                                            const float* __restrict__ vals_p,
                                            bf16x4* __restrict__ Lx4) {
  int w = threadIdx.x >> 6, lane = threadIdx.x & 63;
  int r = blockIdx.x * 4 + w;
  __shared__ int   csm[4][64];
  __shared__ float vsm[4][64];
  int cnt = counts[r];
  const int*   cp = cols_p + (size_t)r * SLOT;
  const float* vp = vals_p + (size_t)r * SLOT;
  float a0 = 0.f, a1 = 0.f, a2 = 0.f, a3 = 0.f;
  float b0 = 0.f, b1 = 0.f, b2 = 0.f, b3 = 0.f;
  for (int base = 0; base < cnt; base += 64) {
    int m = cnt - base; if (m > 64) m = 64;
    if (lane < m) { csm[w][lane] = cp[base + lane]; vsm[w][lane] = vp[base + lane]; }
    int i = 0;
    for (; i + 1 < m; i += 2) {
      bf16x4 xv0 = x0T4[(size_t)csm[w][i]     * 64 + lane];
      bf16x4 xv1 = x0T4[(size_t)csm[w][i + 1] * 64 + lane];
      float v0 = vsm[w][i], v1 = vsm[w][i + 1];
      a0 += v0 * (float)xv0[0]; a1 += v0 * (float)xv0[1];
      a2 += v0 * (float)xv0[2]; a3 += v0 * (float)xv0[3];
      b0 += v1 * (float)xv1[0]; b1 += v1 * (float)xv1[1];
      b2 += v1 * (float)xv1[2]; b3 += v1 * (float)xv1[3];
    }
    if (i < m) {
      bf16x4 xv0 = x0T4[(size_t)csm[w][i] * 64 + lane];
      float v0 = vsm[w][i];
      a0 += v0 * (float)xv0[0]; a1 += v0 * (float)xv0[1];
      a2 += v0 * (float)xv0[2]; a3 += v0 * (float)xv0[3];
    }
  }
  bf16x4 o;
  o[0] = (bf16)(a0 + b0); o[1] = (bf16)(a1 + b1);
  o[2] = (bf16)(a2 + b2); o[3] = (bf16)(a3 + b3);
  Lx4[(size_t)r * 64 + lane] = o;
}

// ---------------- x_t[b][n] = x0[b][n] - 0.5*t[b]*Lx[n][b]   (bf16, B-major)
__global__ __launch_bounds__(256) void k_combine(const float* __restrict__ x0,
                                                 const bf16* __restrict__ Lx,
                                                 const float* __restrict__ t,
                                                 bf16* __restrict__ xt) {
  __shared__ float lxs[64][65];
  int n0 = blockIdx.x * 64, b0 = blockIdx.y * 64;
  int tx = threadIdx.x & 63, ty = threadIdx.x >> 6;
#pragma unroll
  for (int i = 0; i < 16; i++) {
    int nl = ty * 16 + i;
    lxs[nl][tx] = (float)Lx[(size_t)(n0 + nl) * Bb + b0 + tx];
  }
  __syncthreads();
#pragma unroll
  for (int i = 0; i < 16; i++) {
    int bl = ty * 16 + i;
    int b  = b0 + bl;
    float tc = t[b] * 0.5f;   // T_MAX
    float v = x0[(size_t)b * Nn + n0 + tx] - tc * lxs[tx][bl];
    xt[(size_t)b * Nn + n0 + tx] = (bf16)v;
  }
}

// ------------------------------------------------------------- bf16 TN GEMM
// C[m][n] = sum_k A[m][k]*Bm[n][k].
//   MODE 0: store fp32 split-K partial at z*MN
//   MODE 1: direct bf16 store of acc+bias (ACT=1: exact gelu) -> C is bf16*
//   MODE 2: fused loss sum((C+bias-x0)^2)
template <int BM, int BN, int MODE, int ACT = 0>
__global__ __launch_bounds__(256) void gemm_tn(
    const bf16* __restrict__ A, const bf16* __restrict__ Bm,
    float* __restrict__ C, int N, int K, int kLen, int MN,
    const float* __restrict__ bias, const float* __restrict__ x0,
    float* __restrict__ lossOut) {
  constexpr int WM = BM / 2, WN = BN / 2, FM = WM / 16, FN = WN / 16;
  constexpr int PA = (BM * 64) / 4096, PB = (BN * 64) / 4096;
  __shared__ __align__(16) bf16 As[BM * 32];
  __shared__ __align__(16) bf16 Bs[BN * 32];
  const int tid = threadIdx.x;
  const int lane = tid & 63, w = tid >> 6;
  const int wm = w >> 1, wn = w & 1;
  const int mBase = blockIdx.x * BM, nBase = blockIdx.y * BN;
  const int k0 = blockIdx.z * kLen;

  f32x4 acc[FM][FN];
#pragma unroll
  for (int i = 0; i < FM; i++)
#pragma unroll
    for (int j = 0; j < FN; j++) acc[i][j] = {0.f, 0.f, 0.f, 0.f};

  for (int kk = 0; kk < kLen; kk += 32) {
    const int k = k0 + kk;
    __syncthreads();
#pragma unroll
    for (int p = 0; p < PA; p++) {
      int u = p * 256 + tid;  // == p*256 + w*64 + lane
      gload16(A + (size_t)(mBase + (u >> 2)) * K + k + (u & 3) * 8,
              (char*)As + p * 4096 + w * 1024);
    }
#pragma unroll
    for (int p = 0; p < PB; p++) {
      int u = p * 256 + tid;
      gload16(Bm + (size_t)(nBase + (u >> 2)) * K + k + (u & 3) * 8,
              (char*)Bs + p * 4096 + w * 1024);
    }
    __syncthreads();
    bf16x8 af[FM], bfr[FN];
#pragma unroll
    for (int i = 0; i < FM; i++)
      af[i] = *(const bf16x8*)(As + (wm * WM + i * 16 + (lane & 15)) * 32 + (lane >> 4) * 8);
#pragma unroll
    for (int j = 0; j < FN; j++)
      bfr[j] = *(const bf16x8*)(Bs + (wn * WN + j * 16 + (lane & 15)) * 32 + (lane >> 4) * 8);
#pragma unroll
    for (int i = 0; i < FM; i++)
#pragma unroll
      for (int j = 0; j < FN; j++)
        acc[i][j] = __builtin_amdgcn_mfma_f32_16x16x32_bf16(af[i], bfr[j], acc[i][j], 0, 0, 0);
  }

  if constexpr (MODE == 0) {
    float* Cz = C + (size_t)blockIdx.z * MN;
#pragma unroll
    for (int i = 0; i < FM; i++)
#pragma unroll
      for (int j = 0; j < FN; j++) {
        int n  = nBase + wn * WN + j * 16 + (lane & 15);
        int mB = mBase + wm * WM + i * 16 + ((lane >> 4) << 2);
#pragma unroll
        for (int r = 0; r < 4; r++)
          Cz[(size_t)(mB + r) * N + n] = acc[i][j][r];
      }
  } else if constexpr (MODE == 1) {
    bf16* Cb = (bf16*)C;
#pragma unroll
    for (int i = 0; i < FM; i++)
#pragma unroll
      for (int j = 0; j < FN; j++) {
        int n  = nBase + wn * WN + j * 16 + (lane & 15);
        float bo = bias[n];
        int mB = mBase + wm * WM + i * 16 + ((lane >> 4) << 2);
#pragma unroll
        for (int r = 0; r < 4; r++) {
          float x = acc[i][j][r] + bo;
          if constexpr (ACT == 1)
            x = 0.5f * x * (1.f + erff(x * 0.70710678118654752f));
          Cb[(size_t)(mB + r) * N + n] = (bf16)x;
        }
      }
  } else {
    float lsum = 0.f;
#pragma unroll
    for (int i = 0; i < FM; i++)
#pragma unroll
      for (int j = 0; j < FN; j++) {
        int n  = nBase + wn * WN + j * 16 + (lane & 15);
        float bo = bias[n];
        int mB = mBase + wm * WM + i * 16 + ((lane >> 4) << 2);
#pragma unroll
        for (int r = 0; r < 4; r++) {
          float d = acc[i][j][r] + bo - x0[(size_t)(mB + r) * N + n];
          lsum += d * d;
        }
      }
    for (int off = 32; off > 0; off >>= 1) lsum += __shfl_down(lsum, off, 64);
    if (lane == 0) atomicAdd(lossOut, lsum);
  }
}

// ------------- h = sum_32 partials + b_in + time-embed; write fp32 + bf16
__global__ __launch_bounds__(512) void k_epi_h(const float* __restrict__ P,
                                               const float* __restrict__ t,
                                               const float* __restrict__ W_t1,
                                               const float* __restrict__ b_t1,
                                               const float* __restrict__ W_t2,
                                               const float* __restrict__ b_t2,
                                               const float* __restrict__ b_in,
                                               float* __restrict__ h_f32,
                                               bf16* __restrict__ h_b) {
  int b = blockIdx.x, d = threadIdx.x;
  __shared__ float s[32];
  if (d < 32) {
    float z = t[b] * W_t1[d] + b_t1[d];   // t_norm == t
    s[d] = z / (1.f + expf(-z));          // silu
  }
  __syncthreads();
  int i = b * Dd + d;
  float v = b_in[d] + b_t2[d];
#pragma unroll
  for (int sp = 0; sp < 32; sp++) v += P[sp * (Bb * Dd) + i];
#pragma unroll
  for (int j = 0; j < 32; j++) v += s[j] * W_t2[d * 32 + j];
  h_f32[i] = v;
  h_b[i] = (bf16)v;
}

// -------- LayerNorm over D=512: x = base + sum_NS add + bias; y = LN(x)*g+be
template <int NS>
__global__ __launch_bounds__(512) void k_ln(const float* __restrict__ base,
                                            const float* __restrict__ add,
                                            const float* __restrict__ bias,
                                            const float* __restrict__ g,
                                            const float* __restrict__ be,
                                            float* __restrict__ out_f32,
                                            bf16* __restrict__ out_b) {
  int b = blockIdx.x, d = threadIdx.x;
  __shared__ float red[16];
  int i = b * Dd + d;
  float x = base[i] + bias[d];
#pragma unroll
  for (int sp = 0; sp < NS; sp++) x += add[sp * (Bb * Dd) + i];
  int w = d >> 6, lane = d & 63;
  float s = x;
  for (int off = 32; off > 0; off >>= 1) s += __shfl_down(s, off, 64);
  if (lane == 0) red[w] = s;
  __syncthreads();
  if (d == 0) {
    float tot = 0.f;
    for (int q = 0; q < 8; q++) tot += red[q];
    red[8] = tot * (1.f / 512.f);
  }
  __syncthreads();
  float mu = red[8];
  float c = x - mu;
  float s2 = c * c;
  for (int off = 32; off > 0; off >>= 1) s2 += __shfl_down(s2, off, 64);
  if (lane == 0) red[w] = s2;
  __syncthreads();
  if (d == 0) {
    float tot = 0.f;
    for (int q = 0; q < 8; q++) tot += red[q];
    red[8] = tot * (1.f / 512.f);
  }
  __syncthreads();
  float var = red[8];
  float y = c * rsqrtf(var + 1e-5f) * g[d] + be[d];
  if (out_f32) out_f32[i] = y;
  out_b[i] = (bf16)y;
}

__global__ void k_final(const float* __restrict__ loss, float* __restrict__ out) {
  if (threadIdx.x == 0 && blockIdx.x == 0)
    out[0] = loss[0] * (1.f / 4194304.f);  // mean over B*N
}

// ======================================================================= host
extern "C" void kernel_launch(void* const* d_in, const int* in_sizes, int n_in,
                              void* d_out, int out_size, void* d_ws, size_t ws_size,
                              hipStream_t stream) {
  const float* x0    = (const float*)d_in[0];
  const float* t     = (const float*)d_in[1];
  const float* Lv    = (const float*)d_in[2];
  const float* W_in  = (const float*)d_in[3];
  const float* b_in  = (const float*)d_in[4];
  const float* W_out = (const float*)d_in[5];
  const float* b_out = (const float*)d_in[6];
  const float* W_qkv = (const float*)d_in[7];
  const float* b_qkv = (const float*)d_in[8];
  const float* W_o   = (const float*)d_in[9];
  const float* b_o   = (const float*)d_in[10];
  const float* g1    = (const float*)d_in[11];
  const float* be1   = (const float*)d_in[12];
  const float* g2    = (const float*)d_in[13];
  const float* be2   = (const float*)d_in[14];
  const float* W_f1  = (const float*)d_in[15];
  const float* b_f1  = (const float*)d_in[16];
  const float* W_f2  = (const float*)d_in[17];
  const float* b_f2  = (const float*)d_in[18];
  const float* W_t1  = (const float*)d_in[19];
  const float* b_t1  = (const float*)d_in[20];
  const float* W_t2  = (const float*)d_in[21];
  const float* b_t2  = (const float*)d_in[22];
  const int* L_rows  = (const int*)d_in[23];
  const int* L_cols  = (const int*)d_in[24];

  size_t off = 0;
  char* ws = (char*)d_ws;
  auto carve = [&](size_t bytes) -> void* {
    void* p = ws + off;
    off += (bytes + 255) & ~(size_t)255;
    return p;
  };

  bf16* W_in_b   = (bf16*)carve((size_t)Dd * Nn * 2);
  bf16* W_out_b  = (bf16*)carve((size_t)Nn * Dd * 2);
  bf16* W_v_b    = (bf16*)carve((size_t)Dd * Dd * 2);
  bf16* W_o_b    = (bf16*)carve((size_t)Dd * Dd * 2);
  bf16* W_f1_b   = (bf16*)carve((size_t)DFf * Dd * 2);
  bf16* W_f2_b   = (bf16*)carve((size_t)Dd * DFf * 2);
  bf16* x0T_b    = (bf16*)carve((size_t)Nn * Bb * 2);
  bf16* Lx_b     = (bf16*)carve((size_t)Nn * Bb * 2);
  bf16* xt_b     = (bf16*)carve((size_t)Bb * Nn * 2);
  float* p_h     = (float*)carve((size_t)32 * Bb * Dd * 4);   // 16 MB
  float* p_at    = (float*)carve((size_t)Bb * Dd * 4);        // 0.5 MB
  float* p_f2    = (float*)carve((size_t)4 * Bb * Dd * 4);    // 2 MB
  float* h_f32   = (float*)carve((size_t)Bb * Dd * 4);
  bf16* h_b      = (bf16*)carve((size_t)Bb * Dd * 2);
  bf16* v_b      = (bf16*)carve((size_t)Bb * Dd * 2);
  float* hln_f32 = (float*)carve((size_t)Bb * Dd * 4);
  bf16* hln_b    = (bf16*)carve((size_t)Bb * Dd * 2);
  bf16* f1_b     = (bf16*)carve((size_t)Bb * DFf * 2);
  bf16* h2_b     = (bf16*)carve((size_t)Bb * Dd * 2);
  int* counts    = (int*)carve((size_t)Nn * 4);
  float* lossw   = (float*)carve(256);
  int* cols_p    = (int*)carve((size_t)Nn * SLOT * 4);        // 8.4 MB
  float* vals_p  = (float*)carve((size_t)Nn * SLOT * 4);      // 8.4 MB
  (void)in_sizes; (void)n_in; (void)out_size; (void)ws_size;

  // counts + lossw adjacent: one memset covers both
  hipMemsetAsync(counts, 0, (size_t)Nn * 4 + 256, stream);

  // weight conversions fp32->bf16 (single kernel)
  k_cvt_all<<<18944, 256, 0, stream>>>(
      W_in, W_out, W_qkv + (size_t)2 * Dd * Dd, W_o, W_f1, W_f2,
      W_in_b, W_out_b, W_v_b, W_o_b, W_f1_b, W_f2_b);

  // sparse: x0T, padded-bucket CSR, Lx, x_t
  k_transpose<<<dim3(256, 4), 256, 0, stream>>>(x0, x0T_b);
  k_bucket<<<NNZn / 256, 256, 0, stream>>>(L_rows, L_cols, Lv, counts, cols_p, vals_p);
  k_lx<<<Nn / 4, 256, 0, stream>>>((const bf16x4*)x0T_b, counts, cols_p, vals_p,
                                   (bf16x4*)Lx_b);
  k_combine<<<dim3(256, 4), 256, 0, stream>>>(x0, Lx_b, t, xt_b);

  // h = x_t @ W_in^T   (M=256,N=512,K=16384, split-K=32, partial stores)
  gemm_tn<128, 128, 0><<<dim3(2, 4, 32), 256, 0, stream>>>(
      xt_b, W_in_b, p_h, Dd, Nn, 512, Bb * Dd, nullptr, nullptr, nullptr);
  k_epi_h<<<Bb, 512, 0, stream>>>(p_h, t, W_t1, b_t1, W_t2, b_t2, b_in, h_f32, h_b);

  // v = h @ W_qkv_v^T + bias  (K=512, fused bf16 epilogue)
  gemm_tn<64, 64, 1><<<dim3(4, 8, 1), 256, 0, stream>>>(
      h_b, W_v_b, (float*)v_b, Dd, Dd, 512, 0, b_qkv + 2 * Dd, nullptr, nullptr);

  // attn_out = v @ W_o^T  (single fp32 buffer, bias folded into LN)
  gemm_tn<64, 64, 0><<<dim3(4, 8, 1), 256, 0, stream>>>(
      v_b, W_o_b, p_at, Dd, Dd, 512, 0, nullptr, nullptr, nullptr);
  k_ln<1><<<Bb, 512, 0, stream>>>(h_f32, p_at, b_o, g1, be1, hln_f32, hln_b);

  // ff1 = gelu(hln @ W_f1^T + b_f1)  (fused bf16 epilogue)
  gemm_tn<64, 64, 1, 1><<<dim3(4, 32, 1), 256, 0, stream>>>(
      hln_b, W_f1_b, (float*)f1_b, DFf, Dd, 512, 0, b_f1, nullptr, nullptr);

  // ff2 = ff1 @ W_f2^T  (K=2048, split-K=4)
  gemm_tn<64, 64, 0><<<dim3(4, 8, 4), 256, 0, stream>>>(
      f1_b, W_f2_b, p_f2, Dd, DFf, 512, Bb * Dd, nullptr, nullptr, nullptr);
  k_ln<4><<<Bb, 512, 0, stream>>>(hln_f32, p_f2, b_f2, g2, be2, nullptr, h2_b);

  // pred = h2 @ W_out^T + b_out, fused loss
  gemm_tn<128, 128, 2><<<dim3(2, 128, 1), 256, 0, stream>>>(
      h2_b, W_out_b, nullptr, Nn, Dd, 512, 0, b_out, x0, lossw);
  k_final<<<1, 64, 0, stream>>>(lossw, (float*)d_out);
}

// Round 4
// 329.648 us; speedup vs baseline: 1.2220x; 1.0260x over previous
//
#include <hip/hip_runtime.h>
#include <math.h>

// Problem constants
#define Bb   256
#define Nn   16384
#define Dd   512
#define NNZn 540672
#define DFf  2048
#define SLOT 128   // padded CSR bucket width (max row count ~58 for Binom(540672,1/16384))

// k_prep block ranges
#define CVT_BLKS 2560   // middle weights only: 655360 vec4 / 1024
#define TR_BLKS  1024
#define BK_BLKS  2112   // 540672 / 256 exactly

typedef __bf16 bf16;
typedef __bf16 bf16x4 __attribute__((ext_vector_type(4)));
typedef __bf16 bf16x8 __attribute__((ext_vector_type(8)));
typedef float  f32x4  __attribute__((ext_vector_type(4)));

// ---------------------------------------------------------------- async G->LDS
__device__ __forceinline__ void gload16(const void* g, void* l) {
  __builtin_amdgcn_global_load_lds(
      (const __attribute__((address_space(1))) unsigned int*)g,
      (__attribute__((address_space(3))) unsigned int*)l, 16, 0, 0);
}

// ------------- merged prep: middle-weight cvt | x0 transpose | nnz bucketing
__global__ __launch_bounds__(256) void k_prep(
    const float* __restrict__ w_v, const float* __restrict__ w_o,
    const float* __restrict__ w_f1, const float* __restrict__ w_f2,
    bf16* __restrict__ o_v, bf16* __restrict__ o_o,
    bf16* __restrict__ o_f1, bf16* __restrict__ o_f2,
    const float* __restrict__ x0, bf16* __restrict__ x0T,
    const int* __restrict__ rows, const int* __restrict__ cols,
    const float* __restrict__ vals,
    int* __restrict__ counts, int2* __restrict__ ents) {
  __shared__ float tile[64][65];
  int blk = blockIdx.x;
  if (blk < CVT_BLKS) {
    int v = blk * 256 + threadIdx.x;  // vec4 index, 655360 total
    const float* s; bf16* d; int base;
    if (v < 131072) {
      if (v < 65536) { s = w_v;  d = o_v;  base = 0; }
      else           { s = w_o;  d = o_o;  base = 65536; }
    } else {
      if (v < 393216) { s = w_f1; d = o_f1; base = 131072; }
      else            { s = w_f2; d = o_f2; base = 393216; }
    }
    int idx = (v - base) * 4;
    float4 x = *(const float4*)(s + idx);
    bf16x4 o;
    o[0] = (bf16)x.x; o[1] = (bf16)x.y; o[2] = (bf16)x.z; o[3] = (bf16)x.w;
    *(bf16x4*)(d + idx) = o;
  } else if (blk < CVT_BLKS + TR_BLKS) {
    int bx = blk - CVT_BLKS;
    int n0 = (bx & 255) * 64, b0 = (bx >> 8) * 64;
    int tx = threadIdx.x & 63, ty = threadIdx.x >> 6;   // ty 0..3
#pragma unroll
    for (int i = 0; i < 16; i++) {
      int bl = ty * 16 + i;
      tile[bl][tx] = x0[(size_t)(b0 + bl) * Nn + n0 + tx];
    }
    __syncthreads();
#pragma unroll
    for (int i = 0; i < 16; i++) {
      int nl = ty * 16 + i;
      x0T[(size_t)(n0 + nl) * Bb + b0 + tx] = (bf16)tile[tx][nl];
    }
  } else {
    int i = (blk - CVT_BLKS - TR_BLKS) * 256 + threadIdx.x;  // exact: 540672
    int r = rows[i];
    int p = atomicAdd(&counts[r], 1);
    if (p < SLOT)
      ents[(size_t)r * SLOT + p] = make_int2(cols[i], __float_as_int(vals[i]));
  }
}

// ---- Lx[r][:] = sum_j val_j * x0T[col_j][:].  One WAVE per row; each lane
// holds 4 batch elems (bf16x4, 8 B) -> one gather instr = full 512 B row.
__global__ __launch_bounds__(256) void k_lx(const bf16x4* __restrict__ x0T4,
                                            const int* __restrict__ counts,
                                            const int2* __restrict__ ents,
                                            bf16x4* __restrict__ Lx4) {
  int w = threadIdx.x >> 6, lane = threadIdx.x & 63;
  int r = blockIdx.x * 4 + w;
  __shared__ int2 esm[4][64];
  int cnt = counts[r];
  const int2* ep = ents + (size_t)r * SLOT;
  float a0 = 0.f, a1 = 0.f, a2 = 0.f, a3 = 0.f;
  float b0 = 0.f, b1 = 0.f, b2 = 0.f, b3 = 0.f;
  for (int base = 0; base < cnt; base += 64) {
    int m = cnt - base; if (m > 64) m = 64;
    if (lane < m) esm[w][lane] = ep[base + lane];
    int i = 0;
    for (; i + 1 < m; i += 2) {
      int2 e0 = esm[w][i], e1 = esm[w][i + 1];
      bf16x4 xv0 = x0T4[(size_t)e0.x * 64 + lane];
      bf16x4 xv1 = x0T4[(size_t)e1.x * 64 + lane];
      float v0 = __int_as_float(e0.y), v1 = __int_as_float(e1.y);
      a0 += v0 * (float)xv0[0]; a1 += v0 * (float)xv0[1];
      a2 += v0 * (float)xv0[2]; a3 += v0 * (float)xv0[3];
      b0 += v1 * (float)xv1[0]; b1 += v1 * (float)xv1[1];
      b2 += v1 * (float)xv1[2]; b3 += v1 * (float)xv1[3];
    }
    if (i < m) {
      int2 e0 = esm[w][i];
      bf16x4 xv0 = x0T4[(size_t)e0.x * 64 + lane];
      float v0 = __int_as_float(e0.y);
      a0 += v0 * (float)xv0[0]; a1 += v0 * (float)xv0[1];
      a2 += v0 * (float)xv0[2]; a3 += v0 * (float)xv0[3];
    }
  }
  bf16x4 o;
  o[0] = (bf16)(a0 + b0); o[1] = (bf16)(a1 + b1);
  o[2] = (bf16)(a2 + b2); o[3] = (bf16)(a3 + b3);
  Lx4[(size_t)r * 64 + lane] = o;
}

// ---------------- x_t[b][n] = x0[b][n] - 0.5*t[b]*Lx[n][b]   (bf16, B-major)
__global__ __launch_bounds__(256) void k_combine(const float* __restrict__ x0,
                                                 const bf16* __restrict__ Lx,
                                                 const float* __restrict__ t,
                                                 bf16* __restrict__ xt) {
  __shared__ float lxs[64][65];
  int n0 = blockIdx.x * 64, b0 = blockIdx.y * 64;
  int tx = threadIdx.x & 63, ty = threadIdx.x >> 6;
#pragma unroll
  for (int i = 0; i < 16; i++) {
    int nl = ty * 16 + i;
    lxs[nl][tx] = (float)Lx[(size_t)(n0 + nl) * Bb + b0 + tx];
  }
  __syncthreads();
#pragma unroll
  for (int i = 0; i < 16; i++) {
    int bl = ty * 16 + i;
    int b  = b0 + bl;
    float tc = t[b] * 0.5f;   // T_MAX
    float v = x0[(size_t)b * Nn + n0 + tx] - tc * lxs[tx][bl];
    xt[(size_t)b * Nn + n0 + tx] = (bf16)v;
  }
}

// ------------------------------------------------------------- bf16 TN GEMM
// C[m][n] = sum_k A[m][k]*Bm[n][k].
//   MODE 0: store fp32 split-K partial at z*MN
//   MODE 1: direct bf16 store of acc+bias (ACT=1: exact gelu) -> C is bf16*
//   MODE 2: fused loss sum((C+bias-x0)^2)
//   BF32 : B matrix is fp32 in global; convert to bf16 during LDS staging
template <int BM, int BN, int MODE, int ACT = 0, int BF32 = 0>
__global__ __launch_bounds__(256) void gemm_tn(
    const bf16* __restrict__ A, const void* __restrict__ Bmv,
    float* __restrict__ C, int N, int K, int kLen, int MN,
    const float* __restrict__ bias, const float* __restrict__ x0,
    float* __restrict__ lossOut) {
  constexpr int WM = BM / 2, WN = BN / 2, FM = WM / 16, FN = WN / 16;
  constexpr int PA = (BM * 64) / 4096, PB = (BN * 64) / 4096;
  __shared__ __align__(16) bf16 As[BM * 32];
  __shared__ __align__(16) bf16 Bs[BN * 32];
  const int tid = threadIdx.x;
  const int lane = tid & 63, w = tid >> 6;
  const int wm = w >> 1, wn = w & 1;
  const int mBase = blockIdx.x * BM, nBase = blockIdx.y * BN;
  const int k0 = blockIdx.z * kLen;

  f32x4 acc[FM][FN];
#pragma unroll
  for (int i = 0; i < FM; i++)
#pragma unroll
    for (int j = 0; j < FN; j++) acc[i][j] = {0.f, 0.f, 0.f, 0.f};

  for (int kk = 0; kk < kLen; kk += 32) {
    const int k = k0 + kk;
    __syncthreads();
#pragma unroll
    for (int p = 0; p < PA; p++) {
      int u = p * 256 + tid;  // == p*256 + w*64 + lane
      gload16(A + (size_t)(mBase + (u >> 2)) * K + k + (u & 3) * 8,
              (char*)As + p * 4096 + w * 1024);
    }
    if constexpr (BF32) {
      const float* Bf = (const float*)Bmv;
#pragma unroll
      for (int p = 0; p < BN * 32 / 1024; p++) {
        int u = p * 256 + tid;
        int row = u >> 3, sub = u & 7;
        float4 x = *(const float4*)(Bf + (size_t)(nBase + row) * K + k + sub * 4);
        bf16x4 o;
        o[0] = (bf16)x.x; o[1] = (bf16)x.y; o[2] = (bf16)x.z; o[3] = (bf16)x.w;
        *(bf16x4*)(Bs + row * 32 + sub * 4) = o;
      }
    } else {
      const bf16* Bm = (const bf16*)Bmv;
#pragma unroll
      for (int p = 0; p < PB; p++) {
        int u = p * 256 + tid;
        gload16(Bm + (size_t)(nBase + (u >> 2)) * K + k + (u & 3) * 8,
                (char*)Bs + p * 4096 + w * 1024);
      }
    }
    __syncthreads();
    bf16x8 af[FM], bfr[FN];
#pragma unroll
    for (int i = 0; i < FM; i++)
      af[i] = *(const bf16x8*)(As + (wm * WM + i * 16 + (lane & 15)) * 32 + (lane >> 4) * 8);
#pragma unroll
    for (int j = 0; j < FN; j++)
      bfr[j] = *(const bf16x8*)(Bs + (wn * WN + j * 16 + (lane & 15)) * 32 + (lane >> 4) * 8);
#pragma unroll
    for (int i = 0; i < FM; i++)
#pragma unroll
      for (int j = 0; j < FN; j++)
        acc[i][j] = __builtin_amdgcn_mfma_f32_16x16x32_bf16(af[i], bfr[j], acc[i][j], 0, 0, 0);
  }

  if constexpr (MODE == 0) {
    float* Cz = C + (size_t)blockIdx.z * MN;
#pragma unroll
    for (int i = 0; i < FM; i++)
#pragma unroll
      for (int j = 0; j < FN; j++) {
        int n  = nBase + wn * WN + j * 16 + (lane & 15);
        int mB = mBase + wm * WM + i * 16 + ((lane >> 4) << 2);
#pragma unroll
        for (int r = 0; r < 4; r++)
          Cz[(size_t)(mB + r) * N + n] = acc[i][j][r];
      }
  } else if constexpr (MODE == 1) {
    bf16* Cb = (bf16*)C;
#pragma unroll
    for (int i = 0; i < FM; i++)
#pragma unroll
      for (int j = 0; j < FN; j++) {
        int n  = nBase + wn * WN + j * 16 + (lane & 15);
        float bo = bias[n];
        int mB = mBase + wm * WM + i * 16 + ((lane >> 4) << 2);
#pragma unroll
        for (int r = 0; r < 4; r++) {
          float x = acc[i][j][r] + bo;
          if constexpr (ACT == 1)
            x = 0.5f * x * (1.f + erff(x * 0.70710678118654752f));
          Cb[(size_t)(mB + r) * N + n] = (bf16)x;
        }
      }
  } else {
    float lsum = 0.f;
#pragma unroll
    for (int i = 0; i < FM; i++)
#pragma unroll
      for (int j = 0; j < FN; j++) {
        int n  = nBase + wn * WN + j * 16 + (lane & 15);
        float bo = bias[n];
        int mB = mBase + wm * WM + i * 16 + ((lane >> 4) << 2);
#pragma unroll
        for (int r = 0; r < 4; r++) {
          float d = acc[i][j][r] + bo - x0[(size_t)(mB + r) * N + n];
          lsum += d * d;
        }
      }
    for (int off = 32; off > 0; off >>= 1) lsum += __shfl_down(lsum, off, 64);
    if (lane == 0) atomicAdd(lossOut, lsum);
  }
}

// ------------- h = sum_32 partials + b_in + time-embed; write fp32 + bf16
__global__ __launch_bounds__(512) void k_epi_h(const float* __restrict__ P,
                                               const float* __restrict__ t,
                                               const float* __restrict__ W_t1,
                                               const float* __restrict__ b_t1,
                                               const float* __restrict__ W_t2,
                                               const float* __restrict__ b_t2,
                                               const float* __restrict__ b_in,
                                               float* __restrict__ h_f32,
                                               bf16* __restrict__ h_b) {
  int b = blockIdx.x, d = threadIdx.x;
  __shared__ float s[32];
  if (d < 32) {
    float z = t[b] * W_t1[d] + b_t1[d];   // t_norm == t
    s[d] = z / (1.f + expf(-z));          // silu
  }
  __syncthreads();
  int i = b * Dd + d;
  float v = b_in[d] + b_t2[d];
#pragma unroll
  for (int sp = 0; sp < 32; sp++) v += P[sp * (Bb * Dd) + i];
#pragma unroll
  for (int j = 0; j < 32; j++) v += s[j] * W_t2[d * 32 + j];
  h_f32[i] = v;
  h_b[i] = (bf16)v;
}

// -------- LayerNorm over D=512: x = base + sum_NS add + bias; y = LN(x)*g+be
template <int NS>
__global__ __launch_bounds__(512) void k_ln(const float* __restrict__ base,
                                            const float* __restrict__ add,
                                            const float* __restrict__ bias,
                                            const float* __restrict__ g,
                                            const float* __restrict__ be,
                                            float* __restrict__ out_f32,
                                            bf16* __restrict__ out_b) {
  int b = blockIdx.x, d = threadIdx.x;
  __shared__ float red[16];
  int i = b * Dd + d;
  float x = base[i] + bias[d];
#pragma unroll
  for (int sp = 0; sp < NS; sp++) x += add[sp * (Bb * Dd) + i];
  int w = d >> 6, lane = d & 63;
  float s = x;
  for (int off = 32; off > 0; off >>= 1) s += __shfl_down(s, off, 64);
  if (lane == 0) red[w] = s;
  __syncthreads();
  if (d == 0) {
    float tot = 0.f;
    for (int q = 0; q < 8; q++) tot += red[q];
    red[8] = tot * (1.f / 512.f);
  }
  __syncthreads();
  float mu = red[8];
  float c = x - mu;
  float s2 = c * c;
  for (int off = 32; off > 0; off >>= 1) s2 += __shfl_down(s2, off, 64);
  if (lane == 0) red[w] = s2;
  __syncthreads();
  if (d == 0) {
    float tot = 0.f;
    for (int q = 0; q < 8; q++) tot += red[q];
    red[8] = tot * (1.f / 512.f);
  }
  __syncthreads();
  float var = red[8];
  float y = c * rsqrtf(var + 1e-5f) * g[d] + be[d];
  if (out_f32) out_f32[i] = y;
  out_b[i] = (bf16)y;
}

__global__ void k_final(const float* __restrict__ loss, float* __restrict__ out) {
  if (threadIdx.x == 0 && blockIdx.x == 0)
    out[0] = loss[0] * (1.f / 4194304.f);  // mean over B*N
}

// ======================================================================= host
extern "C" void kernel_launch(void* const* d_in, const int* in_sizes, int n_in,
                              void* d_out, int out_size, void* d_ws, size_t ws_size,
                              hipStream_t stream) {
  const float* x0    = (const float*)d_in[0];
  const float* t     = (const float*)d_in[1];
  const float* Lv    = (const float*)d_in[2];
  const float* W_in  = (const float*)d_in[3];
  const float* b_in  = (const float*)d_in[4];
  const float* W_out = (const float*)d_in[5];
  const float* b_out = (const float*)d_in[6];
  const float* W_qkv = (const float*)d_in[7];
  const float* b_qkv = (const float*)d_in[8];
  const float* W_o   = (const float*)d_in[9];
  const float* b_o   = (const float*)d_in[10];
  const float* g1    = (const float*)d_in[11];
  const float* be1   = (const float*)d_in[12];
  const float* g2    = (const float*)d_in[13];
  const float* be2   = (const float*)d_in[14];
  const float* W_f1  = (const float*)d_in[15];
  const float* b_f1  = (const float*)d_in[16];
  const float* W_f2  = (const float*)d_in[17];
  const float* b_f2  = (const float*)d_in[18];
  const float* W_t1  = (const float*)d_in[19];
  const float* b_t1  = (const float*)d_in[20];
  const float* W_t2  = (const float*)d_in[21];
  const float* b_t2  = (const float*)d_in[22];
  const int* L_rows  = (const int*)d_in[23];
  const int* L_cols  = (const int*)d_in[24];

  size_t off = 0;
  char* ws = (char*)d_ws;
  auto carve = [&](size_t bytes) -> void* {
    void* p = ws + off;
    off += (bytes + 255) & ~(size_t)255;
    return p;
  };

  bf16* W_v_b    = (bf16*)carve((size_t)Dd * Dd * 2);
  bf16* W_o_b    = (bf16*)carve((size_t)Dd * Dd * 2);
  bf16* W_f1_b   = (bf16*)carve((size_t)DFf * Dd * 2);
  bf16* W_f2_b   = (bf16*)carve((size_t)Dd * DFf * 2);
  bf16* x0T_b    = (bf16*)carve((size_t)Nn * Bb * 2);
  bf16* Lx_b     = (bf16*)carve((size_t)Nn * Bb * 2);
  bf16* xt_b     = (bf16*)carve((size_t)Bb * Nn * 2);
  float* p_h     = (float*)carve((size_t)32 * Bb * Dd * 4);   // 16 MB
  float* p_at    = (float*)carve((size_t)Bb * Dd * 4);        // 0.5 MB
  float* p_f2    = (float*)carve((size_t)4 * Bb * Dd * 4);    // 2 MB
  float* h_f32   = (float*)carve((size_t)Bb * Dd * 4);
  bf16* h_b      = (bf16*)carve((size_t)Bb * Dd * 2);
  bf16* v_b      = (bf16*)carve((size_t)Bb * Dd * 2);
  float* hln_f32 = (float*)carve((size_t)Bb * Dd * 4);
  bf16* hln_b    = (bf16*)carve((size_t)Bb * Dd * 2);
  bf16* f1_b     = (bf16*)carve((size_t)Bb * DFf * 2);
  bf16* h2_b     = (bf16*)carve((size_t)Bb * Dd * 2);
  int* counts    = (int*)carve((size_t)Nn * 4);
  float* lossw   = (float*)carve(256);
  int2* ents     = (int2*)carve((size_t)Nn * SLOT * 8);       // 16.8 MB
  (void)in_sizes; (void)n_in; (void)out_size; (void)ws_size; (void)Lv;

  // counts + lossw adjacent: one memset covers both
  hipMemsetAsync(counts, 0, (size_t)Nn * 4 + 256, stream);

  // prep: middle-weight cvt | x0 transpose | nnz bucketing (one kernel)
  k_prep<<<CVT_BLKS + TR_BLKS + BK_BLKS, 256, 0, stream>>>(
      W_qkv + (size_t)2 * Dd * Dd, W_o, W_f1, W_f2,
      W_v_b, W_o_b, W_f1_b, W_f2_b,
      x0, x0T_b, L_rows, L_cols, Lv, counts, ents);

  k_lx<<<Nn / 4, 256, 0, stream>>>((const bf16x4*)x0T_b, counts, ents,
                                   (bf16x4*)Lx_b);
  k_combine<<<dim3(256, 4), 256, 0, stream>>>(x0, Lx_b, t, xt_b);

  // h = x_t @ W_in^T   (M=256,N=512,K=16384, split-K=32, fp32-B staging)
  gemm_tn<128, 128, 0, 0, 1><<<dim3(2, 4, 32), 256, 0, stream>>>(
      xt_b, W_in, p_h, Dd, Nn, 512, Bb * Dd, nullptr, nullptr, nullptr);
  k_epi_h<<<Bb, 512, 0, stream>>>(p_h, t, W_t1, b_t1, W_t2, b_t2, b_in, h_f32, h_b);

  // v = h @ W_qkv_v^T + bias  (K=512, fused bf16 epilogue)
  gemm_tn<64, 64, 1><<<dim3(4, 8, 1), 256, 0, stream>>>(
      h_b, W_v_b, (float*)v_b, Dd, Dd, 512, 0, b_qkv + 2 * Dd, nullptr, nullptr);

  // attn_out = v @ W_o^T  (single fp32 buffer, bias folded into LN)
  gemm_tn<64, 64, 0><<<dim3(4, 8, 1), 256, 0, stream>>>(
      v_b, W_o_b, p_at, Dd, Dd, 512, 0, nullptr, nullptr, nullptr);
  k_ln<1><<<Bb, 512, 0, stream>>>(h_f32, p_at, b_o, g1, be1, hln_f32, hln_b);

  // ff1 = gelu(hln @ W_f1^T + b_f1)  (fused bf16 epilogue)
  gemm_tn<64, 64, 1, 1><<<dim3(4, 32, 1), 256, 0, stream>>>(
      hln_b, W_f1_b, (float*)f1_b, DFf, Dd, 512, 0, b_f1, nullptr, nullptr);

  // ff2 = ff1 @ W_f2^T  (K=2048, split-K=4)
  gemm_tn<64, 64, 0><<<dim3(4, 8, 4), 256, 0, stream>>>(
      f1_b, W_f2_b, p_f2, Dd, DFf, 512, Bb * Dd, nullptr, nullptr, nullptr);
  k_ln<4><<<Bb, 512, 0, stream>>>(hln_f32, p_f2, b_f2, g2, be2, nullptr, h2_b);

  // pred = h2 @ W_out^T + b_out, fused loss (fp32-B staging)
  gemm_tn<128, 128, 2, 0, 1><<<dim3(2, 128, 1), 256, 0, stream>>>(
      h2_b, W_out, nullptr, Nn, Dd, 512, 0, b_out, x0, lossw);
  k_final<<<1, 64, 0, stream>>>(lossw, (float*)d_out);
}